// Round 6
// baseline (609.901 us; speedup 1.0000x reference)
//
#include <hip/hip_runtime.h>
#include <hip/hip_bf16.h>

#define N_NODES 100000
#define N_EDGES 3200000
#define IN_C 128
#define HID_C 64
#define OUT_C 64

#define NBUCKET 196          // ceil(N_NODES / 512); bucket = target >> 9
#define SC_EDGES 4096        // edges per scatter block
#define SC_GRID 782          // ceil(E / SC_EDGES)
#define CAP 18432            // padded bucket capacity (mean 16384 + 16 sigma)
#define MM1_GRID (N_NODES / 16)   // 6250 16-row tiles

struct EdgeRec { int s; float v; };   // source node, raw edge weight w

typedef float f32x2 __attribute__((ext_vector_type(2)));
typedef float f32x4 __attribute__((ext_vector_type(4)));
typedef short bf16x8 __attribute__((ext_vector_type(8)));
union F8 { uint4 u; bf16x8 f; };

__device__ __forceinline__ unsigned pack_bf16(float lo, float hi) {
    unsigned short l = __hip_bfloat16_raw(__float2bfloat16(lo)).x;
    unsigned short h = __hip_bfloat16_raw(__float2bfloat16(hi)).x;
    return ((unsigned)h << 16) | l;
}
__device__ __forceinline__ float bf_lo(unsigned u) {
    union { unsigned u; float f; } c; c.u = u << 16; return c.f;
}
__device__ __forceinline__ float bf_hi(unsigned u) {
    union { unsigned u; float f; } c; c.u = u & 0xffff0000u; return c.f;
}
__device__ __forceinline__ f32x2 bfp(unsigned u) {
    union { unsigned u; float f; } lo, hi;
    lo.u = u << 16; hi.u = u & 0xffff0000u;
    f32x2 r; r.x = lo.f; r.y = hi.f; return r;
}
__device__ __forceinline__ void pk_fma(f32x2& acc, f32x2 a, f32x2 w) {
    asm("v_pk_fma_f32 %0, %1, %2, %0" : "+v"(acc) : "v"(a), "v"(w));
}
__device__ __forceinline__ void edge_acc(f32x2* acc2, uint4 u, float w) {
    f32x2 wv; wv.x = w; wv.y = w;
    pk_fma(acc2[0], bfp(u.x), wv);
    pk_fma(acc2[1], bfp(u.y), wv);
    pk_fma(acc2[2], bfp(u.z), wv);
    pk_fma(acc2[3], bfp(u.w), wv);
}
__device__ __forceinline__ unsigned cvt_pk_bf16(float lo, float hi) {
    unsigned r;
    asm("v_cvt_pk_bf16_f32 %0, %1, %2" : "=v"(r) : "v"(lo), "v"(hi));
    return r;
}
__device__ __forceinline__ void split_frag(const float* f, uint4& hi4, uint4& lo4) {
    unsigned hi[4], lo[4];
    #pragma unroll
    for (int p = 0; p < 4; ++p) {
        hi[p] = cvt_pk_bf16(f[2 * p], f[2 * p + 1]);
        float r0 = f[2 * p]     - bf_lo(hi[p]);
        float r1 = f[2 * p + 1] - bf_hi(hi[p]);
        lo[p] = cvt_pk_bf16(r0, r1);
    }
    hi4 = make_uint4(hi[0], hi[1], hi[2], hi[3]);
    lo4 = make_uint4(lo[0], lo[1], lo[2], lo[3]);
}

// ---- per-node degree + weighted degree straight from COO -----------------
// Replaces fine_sort's pass 1 (which re-read all staged edges) and makes
// dis = rsqrt(wdeg+1) available BEFORE the CSR staging, so mm1 can be
// fused with scatter_coarse. 6.4M scattered global atomics, fire-and-forget.
__global__ __launch_bounds__(256) void deg_kernel(const int* __restrict__ ei,
                                                  const float* __restrict__ ew,
                                                  int* __restrict__ deg,
                                                  float* __restrict__ wdeg) {
    int gid = blockIdx.x * 256 + threadIdx.x;        // E/4 threads
    int4   t = ((const int4*)(ei + N_EDGES))[gid];
    float4 w = ((const float4*)ew)[gid];
    atomicAdd(&deg[t.x], 1); atomicAdd(&wdeg[t.x], w.x);
    atomicAdd(&deg[t.y], 1); atomicAdd(&wdeg[t.y], w.y);
    atomicAdd(&deg[t.z], 1); atomicAdd(&wdeg[t.z], w.z);
    atomicAdd(&deg[t.w], 1); atomicAdd(&wdeg[t.w], w.w);
}

// ---- MFMA matmul tile body: h = bf16( dis[row] * (X @ W) ) ---------------
// 3-pass bf16 hi/lo split (Markidis). dis computed on the fly from wdeg.
// One 16-row tile; 4 waves, wave = one 16-col block; all A loads issued
// up front; B fragments built from global W (L2-resident).
template<int K>
__device__ __forceinline__ void mm_tile(int tile,
                                        const float* __restrict__ X,
                                        const float* __restrict__ W,
                                        const float* __restrict__ wdeg,
                                        unsigned* __restrict__ h) {
    constexpr int NKS = K / 32;
    int wv = threadIdx.x >> 6;        // wave id = col-block 0..3
    int l  = threadIdx.x & 63;
    int lr = l & 15;                  // A-row / B-col within tile
    int kr = l >> 4;                  // k sub-block: k = ks*32 + kr*8 + j
    int col = wv * 16 + lr;
    int row0 = tile * 16;
    const float* xbase = X + (size_t)(row0 + lr) * K + kr * 8;
    float4 xa[NKS], xb[NKS];
    #pragma unroll
    for (int ks = 0; ks < NKS; ++ks) {
        const float4* xp = (const float4*)(xbase + ks * 32);
        xa[ks] = xp[0];
        xb[ks] = xp[1];
    }
    F8 bhi[NKS], blo[NKS];
    #pragma unroll
    for (int ks = 0; ks < NKS; ++ks) {
        const float* wp = W + (ks * 32 + kr * 8) * 64 + col;
        float f[8];
        #pragma unroll
        for (int j = 0; j < 8; ++j) f[j] = wp[j * 64];
        split_frag(f, bhi[ks].u, blo[ks].u);
    }
    f32x4 acc = {0.f, 0.f, 0.f, 0.f};
    #pragma unroll
    for (int ks = 0; ks < NKS; ++ks) {
        float f[8] = {xa[ks].x, xa[ks].y, xa[ks].z, xa[ks].w,
                      xb[ks].x, xb[ks].y, xb[ks].z, xb[ks].w};
        F8 ahi, alo;
        split_frag(f, ahi.u, alo.u);
        acc = __builtin_amdgcn_mfma_f32_16x16x32_bf16(ahi.f, bhi[ks].f, acc, 0, 0, 0);
        acc = __builtin_amdgcn_mfma_f32_16x16x32_bf16(ahi.f, blo[ks].f, acc, 0, 0, 0);
        acc = __builtin_amdgcn_mfma_f32_16x16x32_bf16(alo.f, bhi[ks].f, acc, 0, 0, 0);
    }
    int rbase = row0 + kr * 4;
    float v0 = acc[0] * rsqrtf(wdeg[rbase + 0] + 1.0f);
    float v1 = acc[1] * rsqrtf(wdeg[rbase + 1] + 1.0f);
    float v2 = acc[2] * rsqrtf(wdeg[rbase + 2] + 1.0f);
    float v3 = acc[3] * rsqrtf(wdeg[rbase + 3] + 1.0f);
    float o0 = __shfl_xor(v0, 1, 64);
    float o1 = __shfl_xor(v1, 1, 64);
    float o2 = __shfl_xor(v2, 1, 64);
    float o3 = __shfl_xor(v3, 1, 64);
    if ((lr & 1) == 0) {
        int ci = col >> 1;
        h[(rbase + 0) * 32 + ci] = pack_bf16(v0, o0);
        h[(rbase + 1) * 32 + ci] = pack_bf16(v1, o1);
        h[(rbase + 2) * 32 + ci] = pack_bf16(v2, o2);
        h[(rbase + 3) * 32 + ci] = pack_bf16(v3, o3);
    }
}

// ---- FUSED: scatter_coarse (blocks 0..SC_GRID) + mm1 (rest) --------------
// Streams/events are banned under graph capture, so overlap is achieved by
// block-level fusion: 782 scatter blocks dispatch first and fill ~4/CU;
// 6250 mm1 tile-blocks backfill and run concurrently (disjoint outputs:
// tmpPad vs h -- h no longer overlays tmpPad). mm1 depends only on
// x/W1/wdeg, all ready before this launch.
__global__ __launch_bounds__(256) void fused_scatter_mm1(const int* __restrict__ ei,
                                                         const float* __restrict__ ew,
                                                         int* __restrict__ gcursor,
                                                         uint2* __restrict__ tmp,
                                                         const float* __restrict__ x,
                                                         const float* __restrict__ W1,
                                                         const float* __restrict__ wdeg,
                                                         unsigned* __restrict__ h) {
    __shared__ int hist[256];
    __shared__ int scan[256];
    __shared__ int lcur[256];
    __shared__ int adj[256];
    __shared__ uint2 rec[SC_EDGES];           // 32 KB
    __shared__ unsigned char bk[SC_EDGES];    // 4 KB
    if (blockIdx.x >= SC_GRID) {
        mm_tile<IN_C>(blockIdx.x - SC_GRID, x, W1, wdeg, h);
        return;
    }
    int tid = threadIdx.x;
    hist[tid] = 0;
    __syncthreads();
    int base = blockIdx.x * SC_EDGES;
    unsigned ys[16];
    float    ws[16];
    int      bs[16];
    for (int i = 0; i < 16; ++i) {
        int e = base + i * 256 + tid;
        if (e < N_EDGES) {
            int t = ei[N_EDGES + e];
            bs[i] = t >> 9;
            ys[i] = (unsigned)ei[e] | ((unsigned)(t & 511) << 17);
            ws[i] = ew[e];
            atomicAdd(&hist[bs[i]], 1);
        } else bs[i] = -1;
    }
    __syncthreads();
    int v = hist[tid];
    scan[tid] = v;
    __syncthreads();
    for (int off = 1; off < 256; off <<= 1) {
        int t = scan[tid];
        int add = (tid >= off) ? scan[tid - off] : 0;
        __syncthreads();
        scan[tid] = t + add;
        __syncthreads();
    }
    int excl = scan[tid] - v;
    int gb = (v > 0) ? atomicAdd(&gcursor[tid], v) : 0;
    lcur[tid] = excl;
    adj[tid] = tid * CAP + gb - excl;  // global slot for LDS slot j: adj[b]+j
    __syncthreads();
    for (int i = 0; i < 16; ++i) {
        if (bs[i] >= 0) {
            int j = atomicAdd(&lcur[bs[i]], 1);
            rec[j] = make_uint2(__float_as_uint(ws[i]), ys[i]);
            bk[j] = (unsigned char)bs[i];
        }
    }
    __syncthreads();
    int count = N_EDGES - base;
    if (count > SC_EDGES) count = SC_EDGES;
    for (int j = tid; j < count; j += 256) {
        int b = bk[j];
        tmp[adj[b] + j] = rec[j];
    }
}

// ---- layer-2 matmul: standalone one-tile-per-block -----------------------
template<int K>
__global__ __launch_bounds__(256) void mm_mfma(const float* __restrict__ X,
                                               const float* __restrict__ W,
                                               const float* __restrict__ wdeg,
                                               unsigned* __restrict__ h) {
    mm_tile<K>(blockIdx.x, X, W, wdeg, h);
}

// ---- exclusive scan of bucket counts -> dense ed bases -------------------
__global__ __launch_bounds__(256) void bucket_scan(const int* __restrict__ gcnt,
                                                   int* __restrict__ start) {
    __shared__ int s[256];
    int tid = threadIdx.x;
    int v = gcnt[tid];
    s[tid] = v;
    __syncthreads();
    for (int off = 1; off < 256; off <<= 1) {
        int t = s[tid];
        int add = (tid >= off) ? s[tid - off] : 0;
        __syncthreads();
        s[tid] = t + add;
        __syncthreads();
    }
    start[tid] = s[tid] - v;
    if (tid == 255) start[256] = s[255];   // == N_EDGES
}

// ---- per-bucket placement: rowptr from precomputed deg + single pass -----
// fine_sort's pass 1 (edge re-read + LDS count/wdeg atomics) is gone:
// counts come from deg_kernel; scan them in LDS, then place in one pass.
__global__ __launch_bounds__(512) void fine_place(const int* __restrict__ start,
                                                  const int* __restrict__ deg,
                                                  const uint2* __restrict__ tmpPad,
                                                  int* __restrict__ rowptr,
                                                  EdgeRec* __restrict__ ed) {
    __shared__ int cnt[512];
    __shared__ int s[512];
    int tid = threadIdx.x;
    int nodeBase = blockIdx.x << 9;
    int bb = start[blockIdx.x];
    int nEdge = start[blockIdx.x + 1] - bb;
    const uint2* tb = tmpPad + (size_t)blockIdx.x * CAP;
    int node = nodeBase + tid;
    int v = (node < N_NODES) ? deg[node] : 0;
    s[tid] = v;
    __syncthreads();
    for (int off = 1; off < 512; off <<= 1) {
        int t = s[tid];
        int add = (tid >= off) ? s[tid - off] : 0;
        __syncthreads();
        s[tid] = t + add;
        __syncthreads();
    }
    int excl = s[tid] - v;
    if (node < N_NODES) rowptr[node] = bb + excl;
    if (node == N_NODES) rowptr[N_NODES] = N_EDGES;
    cnt[tid] = excl;       // cursor
    __syncthreads();
    for (int e = tid; e < nEdge; e += 512) {
        uint2 r = tb[e];
        int l = (r.y >> 17) & 511;
        int p = atomicAdd(&cnt[l], 1);
        EdgeRec o;
        o.s = (int)(r.y & 0x1FFFFu);
        o.v = __uint_as_float(r.x);
        ed[bb + p] = o;
    }
}

// ---- CSR aggregate + fused epilogue (bf16 dis-scaled h rows, 128 B) ------
// one wave per node; 8 groups of 8 lanes; rows mask-padded to whole
// 32-edge batches (clamped index + zero weight); <=64 VGPR pinned.
__global__ __launch_bounds__(256, 8) void agg_kernel(const int* __restrict__ rowptr,
                                                     const EdgeRec* __restrict__ ed,
                                                     const unsigned* __restrict__ h,
                                                     const float* __restrict__ wdeg,
                                                     const float* __restrict__ b,
                                                     float* __restrict__ out,
                                                     int relu) {
    int node = blockIdx.x * 4 + (threadIdx.x >> 6);
    int lane = threadIdx.x & 63;
    int g = lane >> 3;        // edge group 0..7
    int cl = lane & 7;        // channel octet: channels 8*cl .. 8*cl+7
    int beg = rowptr[node];
    int end = rowptr[node + 1];
    const uint4* h16 = (const uint4*)h;                   // 8 uint4 per row
    const char*  hb  = (const char*)h + (size_t)cl * 16;  // lane's slice base
    float d  = rsqrtf(wdeg[node] + 1.0f);
    uint4 us = h16[(size_t)node * 8 + cl];
    f32x2 acc2[4];
    acc2[0] = 0.f; acc2[1] = 0.f; acc2[2] = 0.f; acc2[3] = 0.f;
    int n = end - beg;            // in-degree (excl self)
    int nb = (n + 31) >> 5;       // 32-edge batches, wave-uniform
    int nm1 = n - 1;
    uint2 q0, q1, q2, q3;
    if (nb > 0) {
        q0 = *(const uint2*)(ed + beg + min(g,      nm1));
        q1 = *(const uint2*)(ed + beg + min(g + 8,  nm1));
        q2 = *(const uint2*)(ed + beg + min(g + 16, nm1));
        q3 = *(const uint2*)(ed + beg + min(g + 24, nm1));
        for (int bt = 0; bt < nb; ++bt) {
            int ob = (bt << 5) + g;
            float w0 = (ob      < n) ? __uint_as_float(q0.y) : 0.f;
            float w1 = (ob + 8  < n) ? __uint_as_float(q1.y) : 0.f;
            float w2 = (ob + 16 < n) ? __uint_as_float(q2.y) : 0.f;
            float w3 = (ob + 24 < n) ? __uint_as_float(q3.y) : 0.f;
            uint4 u0 = *(const uint4*)(hb + ((size_t)(unsigned)q0.x << 7));
            uint4 u1 = *(const uint4*)(hb + ((size_t)(unsigned)q1.x << 7));
            uint4 u2 = *(const uint4*)(hb + ((size_t)(unsigned)q2.x << 7));
            uint4 u3 = *(const uint4*)(hb + ((size_t)(unsigned)q3.x << 7));
            if (bt + 1 < nb) {
                int on = ob + 32;
                q0 = *(const uint2*)(ed + beg + min(on,      nm1));
                q1 = *(const uint2*)(ed + beg + min(on + 8,  nm1));
                q2 = *(const uint2*)(ed + beg + min(on + 16, nm1));
                q3 = *(const uint2*)(ed + beg + min(on + 24, nm1));
            }
            edge_acc(acc2, u0, w0);
            edge_acc(acc2, u1, w1);
            edge_acc(acc2, u2, w2);
            edge_acc(acc2, u3, w3);
        }
    }
    float acc[8] = { acc2[0].x, acc2[0].y, acc2[1].x, acc2[1].y,
                     acc2[2].x, acc2[2].y, acc2[3].x, acc2[3].y };
    #pragma unroll
    for (int kk = 0; kk < 8; ++kk) {
        acc[kk] += __shfl_xor(acc[kk], 8, 64);
        acc[kk] += __shfl_xor(acc[kk], 16, 64);
        acc[kk] += __shfl_xor(acc[kk], 32, 64);
    }
    if (g == 0) {
        float hs[8] = { bf_lo(us.x), bf_hi(us.x), bf_lo(us.y), bf_hi(us.y),
                        bf_lo(us.z), bf_hi(us.z), bf_lo(us.w), bf_hi(us.w) };
        const float4* b4 = (const float4*)b;
        float4 bv0 = b4[cl * 2], bv1 = b4[cl * 2 + 1];
        float4 v0, v1;
        v0.x = d * (acc[0] + hs[0]) + bv0.x;
        v0.y = d * (acc[1] + hs[1]) + bv0.y;
        v0.z = d * (acc[2] + hs[2]) + bv0.z;
        v0.w = d * (acc[3] + hs[3]) + bv0.w;
        v1.x = d * (acc[4] + hs[4]) + bv1.x;
        v1.y = d * (acc[5] + hs[5]) + bv1.y;
        v1.z = d * (acc[6] + hs[6]) + bv1.z;
        v1.w = d * (acc[7] + hs[7]) + bv1.w;
        if (relu) {
            v0.x = fmaxf(v0.x, 0.f); v0.y = fmaxf(v0.y, 0.f);
            v0.z = fmaxf(v0.z, 0.f); v0.w = fmaxf(v0.w, 0.f);
            v1.x = fmaxf(v1.x, 0.f); v1.y = fmaxf(v1.y, 0.f);
            v1.z = fmaxf(v1.z, 0.f); v1.w = fmaxf(v1.w, 0.f);
        }
        float4* o4 = (float4*)out;
        o4[node * 16 + cl * 2]     = v0;
        o4[node * 16 + cl * 2 + 1] = v1;
    }
}

extern "C" void kernel_launch(void* const* d_in, const int* in_sizes, int n_in,
                              void* d_out, int out_size, void* d_ws, size_t ws_size,
                              hipStream_t stream) {
    const float* x  = (const float*)d_in[0];
    const int*   ei = (const int*)d_in[1];   // [2, E]: sources then targets
    const float* ew = (const float*)d_in[2];
    const float* W1 = (const float*)d_in[3];
    const float* b1 = (const float*)d_in[4];
    const float* W2 = (const float*)d_in[5];
    const float* b2 = (const float*)d_in[6];
    float* out = (float*)d_out;

    // workspace carve-up (256 B aligned). h is now OUTSIDE the tmpPad
    // overlay (mm1 writes h concurrently with scatter writing tmpPad);
    // f32 a (25.6 MB) still overlays tmpPad (dead after fine_place).
    char* p = (char*)d_ws;
    auto carve = [&](size_t bytes) { char* r = p; p += (bytes + 255) & ~(size_t)255; return r; };
    int*      rowptr  = (int*)carve((N_NODES + 1) * 4);
    int*      start   = (int*)carve(257 * 4);
    // zeroed region: gcursor + deg + wdeg contiguous, one memset
    char*     z0      = p;
    int*      gcursor = (int*)carve(256 * 4);
    int*      deg     = (int*)carve(N_NODES * 4);
    float*    wdeg    = (float*)carve(N_NODES * 4);
    size_t    zbytes  = (size_t)(p - z0);
    EdgeRec*  ed      = (EdgeRec*)carve((size_t)N_EDGES * 8);
    unsigned* h       = (unsigned*)carve((size_t)N_NODES * 64 * 2);  // 12.8 MB
    size_t    r2sz    = (size_t)NBUCKET * CAP * 8;                   // 28.9 MB
    size_t    asz     = (size_t)N_NODES * 64 * 4;                    // 25.6 MB
    char*     r2      = carve(r2sz > asz ? r2sz : asz);
    uint2*    tmpPad  = (uint2*)r2;
    float*    a       = (float*)r2;

    hipMemsetAsync(z0, 0, zbytes, stream);

    // --- deg/wdeg from COO (unlocks dis AND per-node counts early) ---
    deg_kernel<<<N_EDGES / 1024, 256, 0, stream>>>(ei, ew, deg, wdeg);

    // --- FUSED: CSR coarse scatter  ||  layer-1 matmul ---
    fused_scatter_mm1<<<SC_GRID + MM1_GRID, 256, 0, stream>>>(ei, ew, gcursor,
                                                              tmpPad, x, W1, wdeg, h);
    bucket_scan<<<1, 256, 0, stream>>>(gcursor, start);
    fine_place<<<NBUCKET, 512, 0, stream>>>(start, deg, tmpPad, rowptr, ed);

    // --- layer 1 aggregate: a = relu(agg(h) + b1) ---
    agg_kernel<<<N_NODES / 4, 256, 0, stream>>>(rowptr, ed, h, wdeg, b1, a, 1);

    // --- layer 2: h = bf16(dis.(a@W2)) ; out = agg(h) + b2 ---
    mm_mfma<HID_C><<<N_NODES / 16, 256, 0, stream>>>(a, W2, wdeg, h);
    agg_kernel<<<N_NODES / 4, 256, 0, stream>>>(rowptr, ed, h, wdeg, b2, out, 0);
}

// Round 7
// 357.087 us; speedup vs baseline: 1.7080x; 1.7080x over previous
//
#include <hip/hip_runtime.h>
#include <hip/hip_bf16.h>

#define N_NODES 100000
#define N_EDGES 3200000
#define IN_C 128
#define HID_C 64
#define OUT_C 64

#define NBUCKET 196          // ceil(N_NODES / 512); bucket = target >> 9
#define SC_EDGES 4096        // edges per scatter block
#define SC_GRID 782          // ceil(E / SC_EDGES)
#define CAP 18432            // padded bucket capacity (mean 16384 + 16 sigma)
#define MM1_GRID (N_NODES / 16)   // 6250 16-row tiles

struct EdgeRec { int s; float v; };   // source node, raw edge weight w

typedef float f32x2 __attribute__((ext_vector_type(2)));
typedef float f32x4 __attribute__((ext_vector_type(4)));
typedef short bf16x8 __attribute__((ext_vector_type(8)));
union F8 { uint4 u; bf16x8 f; };

__device__ __forceinline__ unsigned pack_bf16(float lo, float hi) {
    unsigned short l = __hip_bfloat16_raw(__float2bfloat16(lo)).x;
    unsigned short h = __hip_bfloat16_raw(__float2bfloat16(hi)).x;
    return ((unsigned)h << 16) | l;
}
__device__ __forceinline__ float bf_lo(unsigned u) {
    union { unsigned u; float f; } c; c.u = u << 16; return c.f;
}
__device__ __forceinline__ float bf_hi(unsigned u) {
    union { unsigned u; float f; } c; c.u = u & 0xffff0000u; return c.f;
}
__device__ __forceinline__ f32x2 bfp(unsigned u) {
    union { unsigned u; float f; } lo, hi;
    lo.u = u << 16; hi.u = u & 0xffff0000u;
    f32x2 r; r.x = lo.f; r.y = hi.f; return r;
}
__device__ __forceinline__ void pk_fma(f32x2& acc, f32x2 a, f32x2 w) {
    asm("v_pk_fma_f32 %0, %1, %2, %0" : "+v"(acc) : "v"(a), "v"(w));
}
__device__ __forceinline__ void edge_acc(f32x2* acc2, uint4 u, float w) {
    f32x2 wv; wv.x = w; wv.y = w;
    pk_fma(acc2[0], bfp(u.x), wv);
    pk_fma(acc2[1], bfp(u.y), wv);
    pk_fma(acc2[2], bfp(u.z), wv);
    pk_fma(acc2[3], bfp(u.w), wv);
}
__device__ __forceinline__ unsigned cvt_pk_bf16(float lo, float hi) {
    unsigned r;
    asm("v_cvt_pk_bf16_f32 %0, %1, %2" : "=v"(r) : "v"(lo), "v"(hi));
    return r;
}
__device__ __forceinline__ void split_frag(const float* f, uint4& hi4, uint4& lo4) {
    unsigned hi[4], lo[4];
    #pragma unroll
    for (int p = 0; p < 4; ++p) {
        hi[p] = cvt_pk_bf16(f[2 * p], f[2 * p + 1]);
        float r0 = f[2 * p]     - bf_lo(hi[p]);
        float r1 = f[2 * p + 1] - bf_hi(hi[p]);
        lo[p] = cvt_pk_bf16(r0, r1);
    }
    hi4 = make_uint4(hi[0], hi[1], hi[2], hi[3]);
    lo4 = make_uint4(lo[0], lo[1], lo[2], lo[3]);
}

// ---- scatter body: edges -> padded bucket-major staging (LDS sort) -------
__device__ __forceinline__ void scatter_body(const int* __restrict__ ei,
                                             const float* __restrict__ ew,
                                             int* __restrict__ gcursor,
                                             uint2* __restrict__ tmp,
                                             int* hist, int* scn, int* lcur,
                                             int* adj, uint2* rec,
                                             unsigned char* bk) {
    int tid = threadIdx.x;
    hist[tid] = 0;
    __syncthreads();
    int base = blockIdx.x * SC_EDGES;
    unsigned ys[16];
    float    ws[16];
    int      bs[16];
    for (int i = 0; i < 16; ++i) {
        int e = base + i * 256 + tid;
        if (e < N_EDGES) {
            int t = ei[N_EDGES + e];
            bs[i] = t >> 9;
            ys[i] = (unsigned)ei[e] | ((unsigned)(t & 511) << 17);
            ws[i] = ew[e];
            atomicAdd(&hist[bs[i]], 1);
        } else bs[i] = -1;
    }
    __syncthreads();
    int v = hist[tid];
    scn[tid] = v;
    __syncthreads();
    for (int off = 1; off < 256; off <<= 1) {
        int t = scn[tid];
        int add = (tid >= off) ? scn[tid - off] : 0;
        __syncthreads();
        scn[tid] = t + add;
        __syncthreads();
    }
    int excl = scn[tid] - v;
    int gb = (v > 0) ? atomicAdd(&gcursor[tid], v) : 0;
    lcur[tid] = excl;
    adj[tid] = tid * CAP + gb - excl;  // global slot for LDS slot j: adj[b]+j
    __syncthreads();
    for (int i = 0; i < 16; ++i) {
        if (bs[i] >= 0) {
            int j = atomicAdd(&lcur[bs[i]], 1);
            rec[j] = make_uint2(__float_as_uint(ws[i]), ys[i]);
            bk[j] = (unsigned char)bs[i];
        }
    }
    __syncthreads();
    int count = N_EDGES - base;
    if (count > SC_EDGES) count = SC_EDGES;
    for (int j = tid; j < count; j += 256) {
        int b = bk[j];
        tmp[adj[b] + j] = rec[j];
    }
}

// ---- MFMA tile body, RAW mode: hf32 = X @ W (no dis, f32 store) ----------
// 3-pass bf16 hi/lo split; one 16-row tile; 4 waves = 4 col-blocks.
template<int K>
__device__ __forceinline__ void mm_tile_raw(int tile,
                                            const float* __restrict__ X,
                                            const float* __restrict__ W,
                                            float* __restrict__ hf) {
    constexpr int NKS = K / 32;
    int wv = threadIdx.x >> 6;
    int l  = threadIdx.x & 63;
    int lr = l & 15;
    int kr = l >> 4;
    int col = wv * 16 + lr;
    int row0 = tile * 16;
    const float* xbase = X + (size_t)(row0 + lr) * K + kr * 8;
    float4 xa[NKS], xb[NKS];
    #pragma unroll
    for (int ks = 0; ks < NKS; ++ks) {
        const float4* xp = (const float4*)(xbase + ks * 32);
        xa[ks] = xp[0];
        xb[ks] = xp[1];
    }
    F8 bhi[NKS], blo[NKS];
    #pragma unroll
    for (int ks = 0; ks < NKS; ++ks) {
        const float* wp = W + (ks * 32 + kr * 8) * 64 + col;
        float f[8];
        #pragma unroll
        for (int j = 0; j < 8; ++j) f[j] = wp[j * 64];
        split_frag(f, bhi[ks].u, blo[ks].u);
    }
    f32x4 acc = {0.f, 0.f, 0.f, 0.f};
    #pragma unroll
    for (int ks = 0; ks < NKS; ++ks) {
        float f[8] = {xa[ks].x, xa[ks].y, xa[ks].z, xa[ks].w,
                      xb[ks].x, xb[ks].y, xb[ks].z, xb[ks].w};
        F8 ahi, alo;
        split_frag(f, ahi.u, alo.u);
        acc = __builtin_amdgcn_mfma_f32_16x16x32_bf16(ahi.f, bhi[ks].f, acc, 0, 0, 0);
        acc = __builtin_amdgcn_mfma_f32_16x16x32_bf16(ahi.f, blo[ks].f, acc, 0, 0, 0);
        acc = __builtin_amdgcn_mfma_f32_16x16x32_bf16(alo.f, bhi[ks].f, acc, 0, 0, 0);
    }
    int rbase = row0 + kr * 4;
    hf[(size_t)(rbase + 0) * 64 + col] = acc[0];
    hf[(size_t)(rbase + 1) * 64 + col] = acc[1];
    hf[(size_t)(rbase + 2) * 64 + col] = acc[2];
    hf[(size_t)(rbase + 3) * 64 + col] = acc[3];
}

// ---- FUSED: scatter_coarse (blocks < SC_GRID) || raw mm1 (rest) ----------
// mm1-unscaled depends only on x/W1 => fully independent of the CSR build.
// 782 scatter blocks dispatch first and fill the CUs; 6250 MFMA tile-blocks
// backfill and run on the idle MFMA/VALU pipes under scatter's mem phase.
__global__ __launch_bounds__(256) void fused_scatter_mm1(const int* __restrict__ ei,
                                                         const float* __restrict__ ew,
                                                         int* __restrict__ gcursor,
                                                         uint2* __restrict__ tmp,
                                                         const float* __restrict__ x,
                                                         const float* __restrict__ W1,
                                                         float* __restrict__ hf) {
    __shared__ int hist[256];
    __shared__ int scn[256];
    __shared__ int lcur[256];
    __shared__ int adj[256];
    __shared__ uint2 rec[SC_EDGES];           // 32 KB
    __shared__ unsigned char bk[SC_EDGES];    // 4 KB
    if (blockIdx.x >= SC_GRID) {
        mm_tile_raw<IN_C>(blockIdx.x - SC_GRID, x, W1, hf);
        return;
    }
    scatter_body(ei, ew, gcursor, tmp, hist, scn, lcur, adj, rec, bk);
}

// ---- standalone scatter (slow path) --------------------------------------
__global__ __launch_bounds__(256) void scatter_coarse(const int* __restrict__ ei,
                                                      const float* __restrict__ ew,
                                                      int* __restrict__ gcursor,
                                                      uint2* __restrict__ tmp) {
    __shared__ int hist[256];
    __shared__ int scn[256];
    __shared__ int lcur[256];
    __shared__ int adj[256];
    __shared__ uint2 rec[SC_EDGES];
    __shared__ unsigned char bk[SC_EDGES];
    scatter_body(ei, ew, gcursor, tmp, hist, scn, lcur, adj, rec, bk);
}

// ---- scale + pack: h = bf16(dis[row] * hf32)  (bitwise == baseline) ------
__global__ __launch_bounds__(256) void scalepack(const float* __restrict__ hf,
                                                 const float* __restrict__ dis,
                                                 unsigned* __restrict__ h) {
    int t = blockIdx.x * 256 + threadIdx.x;   // N_NODES*8 threads
    int row = t >> 3, c8 = (t & 7) * 8;
    const float4* p4 = (const float4*)(hf + (size_t)row * 64 + c8);
    float4 f0 = p4[0], f1 = p4[1];
    float d = dis[row];
    uint4 o;
    o.x = pack_bf16(d * f0.x, d * f0.y);
    o.y = pack_bf16(d * f0.z, d * f0.w);
    o.z = pack_bf16(d * f1.x, d * f1.y);
    o.w = pack_bf16(d * f1.z, d * f1.w);
    ((uint4*)h)[(size_t)row * 8 + (t & 7)] = o;
}

// ---- MFMA matmul, scaled+packed, grid-stride w/ hoisted B (R3 config) ----
template<int K>
__global__ __launch_bounds__(256) void mm_mfma(const float* __restrict__ X,
                                               const float* __restrict__ W,
                                               const float* __restrict__ dis,
                                               unsigned* __restrict__ h) {
    constexpr int NKS = K / 32;
    int wv = threadIdx.x >> 6;
    int l  = threadIdx.x & 63;
    int lr = l & 15;
    int kr = l >> 4;
    int col = wv * 16 + lr;
    F8 bhi[NKS], blo[NKS];
    #pragma unroll
    for (int ks = 0; ks < NKS; ++ks) {
        const float* wp = W + (ks * 32 + kr * 8) * 64 + col;
        float f[8];
        #pragma unroll
        for (int j = 0; j < 8; ++j) f[j] = wp[j * 64];
        split_frag(f, bhi[ks].u, blo[ks].u);
    }
    for (int t = blockIdx.x; t < N_NODES / 16; t += gridDim.x) {
        int row0 = t * 16;
        f32x4 acc = {0.f, 0.f, 0.f, 0.f};
        #pragma unroll
        for (int ks = 0; ks < NKS; ++ks) {
            const float4* xp = (const float4*)(X + (size_t)(row0 + lr) * K + ks * 32 + kr * 8);
            float4 fa = xp[0], fb = xp[1];
            float f[8] = {fa.x, fa.y, fa.z, fa.w, fb.x, fb.y, fb.z, fb.w};
            F8 ahi, alo;
            split_frag(f, ahi.u, alo.u);
            acc = __builtin_amdgcn_mfma_f32_16x16x32_bf16(ahi.f, bhi[ks].f, acc, 0, 0, 0);
            acc = __builtin_amdgcn_mfma_f32_16x16x32_bf16(ahi.f, blo[ks].f, acc, 0, 0, 0);
            acc = __builtin_amdgcn_mfma_f32_16x16x32_bf16(alo.f, bhi[ks].f, acc, 0, 0, 0);
        }
        int rbase = row0 + kr * 4;
        float v0 = acc[0] * dis[rbase + 0];
        float v1 = acc[1] * dis[rbase + 1];
        float v2 = acc[2] * dis[rbase + 2];
        float v3 = acc[3] * dis[rbase + 3];
        float o0 = __shfl_xor(v0, 1, 64);
        float o1 = __shfl_xor(v1, 1, 64);
        float o2 = __shfl_xor(v2, 1, 64);
        float o3 = __shfl_xor(v3, 1, 64);
        if ((lr & 1) == 0) {
            int ci = col >> 1;
            h[(rbase + 0) * 32 + ci] = pack_bf16(v0, o0);
            h[(rbase + 1) * 32 + ci] = pack_bf16(v1, o1);
            h[(rbase + 2) * 32 + ci] = pack_bf16(v2, o2);
            h[(rbase + 3) * 32 + ci] = pack_bf16(v3, o3);
        }
    }
}

// ---- exclusive scan of bucket counts -> dense ed bases -------------------
__global__ __launch_bounds__(256) void bucket_scan(const int* __restrict__ gcnt,
                                                   int* __restrict__ start) {
    __shared__ int s[256];
    int tid = threadIdx.x;
    int v = gcnt[tid];
    s[tid] = v;
    __syncthreads();
    for (int off = 1; off < 256; off <<= 1) {
        int t = s[tid];
        int add = (tid >= off) ? s[tid - off] : 0;
        __syncthreads();
        s[tid] = t + add;
        __syncthreads();
    }
    start[tid] = s[tid] - v;
    if (tid == 255) start[256] = s[255];   // == N_EDGES
}

// ---- per-bucket counting sort + rowptr + dis (one block per bucket) ------
__global__ __launch_bounds__(512) void fine_sort(const int* __restrict__ start,
                                                 const uint2* __restrict__ tmpPad,
                                                 int* __restrict__ rowptr,
                                                 float* __restrict__ dis,
                                                 EdgeRec* __restrict__ ed) {
    __shared__ int   cnt[512];
    __shared__ float wdeg[512];
    __shared__ int   s[512];
    int tid = threadIdx.x;
    int nodeBase = blockIdx.x << 9;
    int bb = start[blockIdx.x];
    int nEdge = start[blockIdx.x + 1] - bb;
    const uint2* tb = tmpPad + (size_t)blockIdx.x * CAP;
    cnt[tid] = 0;
    wdeg[tid] = 0.f;
    __syncthreads();
    for (int e = tid; e < nEdge; e += 512) {
        uint2 r = tb[e];
        int l = (r.y >> 17) & 511;
        atomicAdd(&cnt[l], 1);
        atomicAdd(&wdeg[l], __uint_as_float(r.x));
    }
    __syncthreads();
    int v = cnt[tid];
    s[tid] = v;
    __syncthreads();
    for (int off = 1; off < 512; off <<= 1) {
        int t = s[tid];
        int add = (tid >= off) ? s[tid - off] : 0;
        __syncthreads();
        s[tid] = t + add;
        __syncthreads();
    }
    int excl = s[tid] - v;
    int node = nodeBase + tid;
    if (node < N_NODES) {
        rowptr[node] = bb + excl;
        dis[node] = rsqrtf(wdeg[tid] + 1.0f);   // +1 = self-loop weight
    }
    if (node == N_NODES) rowptr[N_NODES] = N_EDGES;
    cnt[tid] = excl;       // reuse as cursor
    __syncthreads();
    for (int e = tid; e < nEdge; e += 512) {
        uint2 r = tb[e];
        int l = (r.y >> 17) & 511;
        int p = atomicAdd(&cnt[l], 1);
        EdgeRec o;
        o.s = (int)(r.y & 0x1FFFFu);
        o.v = __uint_as_float(r.x);
        ed[bb + p] = o;
    }
}

// ---- CSR aggregate + fused epilogue (bf16 dis-scaled h rows, 128 B) ------
// one wave per node; 8 groups of 8 lanes; rows mask-padded to whole
// 32-edge batches (clamped index + zero weight); <=64 VGPR pinned.
__global__ __launch_bounds__(256, 8) void agg_kernel(const int* __restrict__ rowptr,
                                                     const EdgeRec* __restrict__ ed,
                                                     const unsigned* __restrict__ h,
                                                     const float* __restrict__ dis,
                                                     const float* __restrict__ b,
                                                     float* __restrict__ out,
                                                     int relu) {
    int node = blockIdx.x * 4 + (threadIdx.x >> 6);
    int lane = threadIdx.x & 63;
    int g = lane >> 3;        // edge group 0..7
    int cl = lane & 7;        // channel octet: channels 8*cl .. 8*cl+7
    int beg = rowptr[node];
    int end = rowptr[node + 1];
    const uint4* h16 = (const uint4*)h;                   // 8 uint4 per row
    const char*  hb  = (const char*)h + (size_t)cl * 16;  // lane's slice base
    float d  = dis[node];
    uint4 us = h16[(size_t)node * 8 + cl];
    f32x2 acc2[4];
    acc2[0] = 0.f; acc2[1] = 0.f; acc2[2] = 0.f; acc2[3] = 0.f;
    int n = end - beg;            // in-degree (excl self)
    int nb = (n + 31) >> 5;       // 32-edge batches, wave-uniform
    int nm1 = n - 1;
    uint2 q0, q1, q2, q3;
    if (nb > 0) {
        q0 = *(const uint2*)(ed + beg + min(g,      nm1));
        q1 = *(const uint2*)(ed + beg + min(g + 8,  nm1));
        q2 = *(const uint2*)(ed + beg + min(g + 16, nm1));
        q3 = *(const uint2*)(ed + beg + min(g + 24, nm1));
        for (int bt = 0; bt < nb; ++bt) {
            int ob = (bt << 5) + g;
            float w0 = (ob      < n) ? __uint_as_float(q0.y) : 0.f;
            float w1 = (ob + 8  < n) ? __uint_as_float(q1.y) : 0.f;
            float w2 = (ob + 16 < n) ? __uint_as_float(q2.y) : 0.f;
            float w3 = (ob + 24 < n) ? __uint_as_float(q3.y) : 0.f;
            uint4 u0 = *(const uint4*)(hb + ((size_t)(unsigned)q0.x << 7));
            uint4 u1 = *(const uint4*)(hb + ((size_t)(unsigned)q1.x << 7));
            uint4 u2 = *(const uint4*)(hb + ((size_t)(unsigned)q2.x << 7));
            uint4 u3 = *(const uint4*)(hb + ((size_t)(unsigned)q3.x << 7));
            if (bt + 1 < nb) {
                int on = ob + 32;
                q0 = *(const uint2*)(ed + beg + min(on,      nm1));
                q1 = *(const uint2*)(ed + beg + min(on + 8,  nm1));
                q2 = *(const uint2*)(ed + beg + min(on + 16, nm1));
                q3 = *(const uint2*)(ed + beg + min(on + 24, nm1));
            }
            edge_acc(acc2, u0, w0);
            edge_acc(acc2, u1, w1);
            edge_acc(acc2, u2, w2);
            edge_acc(acc2, u3, w3);
        }
    }
    float acc[8] = { acc2[0].x, acc2[0].y, acc2[1].x, acc2[1].y,
                     acc2[2].x, acc2[2].y, acc2[3].x, acc2[3].y };
    #pragma unroll
    for (int kk = 0; kk < 8; ++kk) {
        acc[kk] += __shfl_xor(acc[kk], 8, 64);
        acc[kk] += __shfl_xor(acc[kk], 16, 64);
        acc[kk] += __shfl_xor(acc[kk], 32, 64);
    }
    if (g == 0) {
        float hs[8] = { bf_lo(us.x), bf_hi(us.x), bf_lo(us.y), bf_hi(us.y),
                        bf_lo(us.z), bf_hi(us.z), bf_lo(us.w), bf_hi(us.w) };
        const float4* b4 = (const float4*)b;
        float4 bv0 = b4[cl * 2], bv1 = b4[cl * 2 + 1];
        float4 v0, v1;
        v0.x = d * (acc[0] + hs[0]) + bv0.x;
        v0.y = d * (acc[1] + hs[1]) + bv0.y;
        v0.z = d * (acc[2] + hs[2]) + bv0.z;
        v0.w = d * (acc[3] + hs[3]) + bv0.w;
        v1.x = d * (acc[4] + hs[4]) + bv1.x;
        v1.y = d * (acc[5] + hs[5]) + bv1.y;
        v1.z = d * (acc[6] + hs[6]) + bv1.z;
        v1.w = d * (acc[7] + hs[7]) + bv1.w;
        if (relu) {
            v0.x = fmaxf(v0.x, 0.f); v0.y = fmaxf(v0.y, 0.f);
            v0.z = fmaxf(v0.z, 0.f); v0.w = fmaxf(v0.w, 0.f);
            v1.x = fmaxf(v1.x, 0.f); v1.y = fmaxf(v1.y, 0.f);
            v1.z = fmaxf(v1.z, 0.f); v1.w = fmaxf(v1.w, 0.f);
        }
        float4* o4 = (float4*)out;
        o4[node * 16 + cl * 2]     = v0;
        o4[node * 16 + cl * 2 + 1] = v1;
    }
}

extern "C" void kernel_launch(void* const* d_in, const int* in_sizes, int n_in,
                              void* d_out, int out_size, void* d_ws, size_t ws_size,
                              hipStream_t stream) {
    const float* x  = (const float*)d_in[0];
    const int*   ei = (const int*)d_in[1];   // [2, E]: sources then targets
    const float* ew = (const float*)d_in[2];
    const float* W1 = (const float*)d_in[3];
    const float* b1 = (const float*)d_in[4];
    const float* W2 = (const float*)d_in[5];
    const float* b2 = (const float*)d_in[6];
    float* out = (float*)d_out;

    char* p = (char*)d_ws;
    auto carve = [&](size_t bytes) { char* r = p; p += (bytes + 255) & ~(size_t)255; return r; };
    int*      rowptr  = (int*)carve((N_NODES + 1) * 4);
    int*      start   = (int*)carve(257 * 4);
    int*      gcursor = (int*)carve(256 * 4);
    float*    dis     = (float*)carve(N_NODES * 4);
    EdgeRec*  ed      = (EdgeRec*)carve((size_t)N_EDGES * 8);          // 25.6 MB
    unsigned* h       = (unsigned*)carve((size_t)N_NODES * 64 * 2);    // 12.8 MB

    size_t tmpsz = (size_t)NBUCKET * CAP * 8;                          // 28.9 MB
    size_t hfsz  = (size_t)N_NODES * 64 * 4;                           // 25.6 MB
    size_t used  = (size_t)(p - (char*)d_ws);
    bool fast = ws_size >= used + hfsz + tmpsz + 512;

    if (fast) {
        // fast layout: hf32 (a overlays it later) + tmpPad both live.
        float* hf     = (float*)carve(hfsz);
        uint2* tmpPad = (uint2*)carve(tmpsz);
        float* a      = hf;          // hf32 dead after scalepack; agg1 writes a

        hipMemsetAsync(gcursor, 0, 256 * sizeof(int), stream);
        // CSR coarse scatter || raw layer-1 matmul (independent of CSR)
        fused_scatter_mm1<<<SC_GRID + MM1_GRID, 256, 0, stream>>>(ei, ew, gcursor,
                                                                  tmpPad, x, W1, hf);
        bucket_scan<<<1, 256, 0, stream>>>(gcursor, start);
        fine_sort<<<NBUCKET, 512, 0, stream>>>(start, tmpPad, rowptr, dis, ed);
        // h = bf16(dis * hf32)  -- bitwise identical to baseline epilogue
        scalepack<<<N_NODES * 8 / 256, 256, 0, stream>>>(hf, dis, h);
        agg_kernel<<<N_NODES / 4, 256, 0, stream>>>(rowptr, ed, h, dis, b1, a, 1);
        mm_mfma<HID_C><<<1250, 256, 0, stream>>>(a, W2, dis, h);
        agg_kernel<<<N_NODES / 4, 256, 0, stream>>>(rowptr, ed, h, dis, b2, out, 0);
    } else {
        // slow/serial fallback (known-fit 68 MB layout, R4 structure)
        size_t asz = (size_t)N_NODES * 64 * 4;
        char*  r2  = carve(tmpsz > asz ? tmpsz : asz);
        uint2* tmpPad = (uint2*)r2;
        float* a      = (float*)r2;

        hipMemsetAsync(gcursor, 0, 256 * sizeof(int), stream);
        scatter_coarse<<<SC_GRID, 256, 0, stream>>>(ei, ew, gcursor, tmpPad);
        bucket_scan<<<1, 256, 0, stream>>>(gcursor, start);
        fine_sort<<<NBUCKET, 512, 0, stream>>>(start, tmpPad, rowptr, dis, ed);
        mm_mfma<IN_C><<<1250, 256, 0, stream>>>(x, W1, dis, h);
        agg_kernel<<<N_NODES / 4, 256, 0, stream>>>(rowptr, ed, h, dis, b1, a, 1);
        mm_mfma<HID_C><<<1250, 256, 0, stream>>>(a, W2, dis, h);
        agg_kernel<<<N_NODES / 4, 256, 0, stream>>>(rowptr, ed, h, dis, b2, out, 0);
    }
}